// Round 5
// baseline (628.389 us; speedup 1.0000x reference)
//
#include <hip/hip_runtime.h>
#include <hip/hip_bf16.h>
#include <cstdint>

#define B_IMG   8
#define NCAND   36720
#define PD      85
#define NCLS    80
#define KC      512
#define MAXDET  300
#define NBUCK   2048
#define CANDCAP 1024      // gathered count is ~512 + one-bucket (<~30): 1024 is safe
#define PX1     9216      // 96*96 pixels, level 1 (bf16 G1)
#define PXA     3024      // 48*48 + 24*24 + 12*12, levels 2-4 (f32 Gacc)

typedef unsigned int u32;
typedef unsigned long long u64;

__device__ __forceinline__ float leaky(float x){ return x >= 0.f ? x : 0.01f*x; }

__device__ __forceinline__ u64 shfl_u64(u64 v, int lane){
  int lo = __shfl((int)(u32)(v & 0xFFFFFFFFull), lane, 64);
  int hi = __shfl((int)(u32)(v >> 32), lane, 64);
  return ((u64)(u32)hi << 32) | (u64)(u32)lo;
}
__device__ __forceinline__ u64 shfl_xor_u64(u64 v, int mask){
  int lo = __shfl_xor((int)(u32)(v & 0xFFFFFFFFull), mask, 64);
  int hi = __shfl_xor((int)(u32)(v >> 32), mask, 64);
  return ((u64)(u32)hi << 32) | (u64)(u32)lo;
}

// ---------------- K1: score + argmax-cls, 4 lanes/candidate, no LDS ----------------
// Quad lane q scans classes {q, q+4, ..., q+76} (16B contiguous per quad per
// step -> 16-32 lines per instr, L1-cached region). u64 key (bits<<32)|~cls
// gives JAX argmax tie-break (first max) under max-reduce. No LDS -> full
// occupancy (vs old 21.7KB tile capping 7 waves/CU).
__global__ __launch_bounds__(256) void k_score(const float* __restrict__ preds,
    u32* __restrict__ sbits, int* __restrict__ clsArr, u32* __restrict__ hist){
  const int img = blockIdx.y;
  const int tid = threadIdx.x;
  const int q   = tid & 3;
  const int ci  = blockIdx.x*64 + (tid >> 2);
  if (ci >= NCAND) return;
  const float* p = preds + ((long)img*NCAND + ci)*PD;
  float obj = p[4];
  const float* pc = p + 5 + q;
  u64 best = 0ull;
  #pragma unroll
  for (int k = 0; k < 20; k++){
    float v = pc[4*k] * obj;
    u32 cls = (u32)(q + 4*k);
    u64 key = ((u64)__float_as_uint(v) << 32) | (u64)(~cls);
    if (key > best) best = key;     // strict >: first max wins within lane
  }
  #pragma unroll
  for (int off = 1; off <= 2; off <<= 1){
    u64 o = shfl_xor_u64(best, off);
    if (o > best) best = o;         // tie: larger ~cls = smaller cls wins
  }
  if (q == 0){
    u32 bits = (u32)(best >> 32);
    bool valid = (obj > 0.596f) && (__uint_as_float(bits) > 0.596f);
    u32 sb = valid ? bits : 0u;     // valid scores in (0.596,1)
    int cls = (int)(~(u32)(best & 0xFFFFFFFFull));
    long gi = (long)img*NCAND + ci;
    sbits[gi]  = sb;
    clsArr[gi] = cls;
    if (sb) atomicAdd(&hist[img*NBUCK + ((sb - 0x3F000000u) >> 12)], 1u);
  }
}

// ---------------- K2: per-image bit-threshold covering top-512 ----------------
__global__ __launch_bounds__(64) void k_thresh(const u32* __restrict__ hist,
                                               u32* __restrict__ thr){
  const int img = blockIdx.x;
  const int lane = threadIdx.x;
  const u32* h = hist + img*NBUCK;
  u32 acc = 0; u32 result = 0x3F000000u; bool found = false;
  for (int g = NBUCK/64 - 1; g >= 0 && !found; g--){
    u32 v = h[g*64 + lane];
    u32 s = v;
    #pragma unroll
    for (int off = 1; off < 64; off <<= 1){
      u32 t = __shfl_down(s, off, 64);
      s += (lane + off < 64) ? t : 0u;
    }
    u64 mask = __ballot(acc + s >= KC);
    if (mask){
      int hl = 63 - __clzll(mask);
      result = 0x3F000000u + ((u32)(g*64 + hl) << 12);
      found = true;
    }
    acc += __shfl(s, 0, 64);
  }
  if (lane == 0) thr[img] = result;
}

// ---------------- K3: gather candidates >= threshold as sortable keys ----------------
__global__ __launch_bounds__(256) void k_gather(const u32* __restrict__ sbits,
    const u32* __restrict__ thr, u32* __restrict__ cnt, u64* __restrict__ cand){
  int img = blockIdx.y;
  int n = blockIdx.x*256 + threadIdx.x;
  if (n >= NCAND) return;
  u32 bits = sbits[(long)img*NCAND + n];
  if (bits && bits >= thr[img]){
    u32 pos = atomicAdd(&cnt[img], 1u);
    if (pos < CANDCAP)
      cand[(long)img*CANDCAP + pos] = ((u64)bits << 32) | (u64)(0xFFFFFFFFu - (u32)n);
  }
}

// ---------------- K4a: bitonic sort 1024 -> decode top-512 boxes to global ----------------
__global__ __launch_bounds__(512) void k_sort(const float* __restrict__ preds,
    const int* __restrict__ clsArr, const u64* __restrict__ cand,
    const u32* __restrict__ cnt, float4* __restrict__ cboxg,
    float4* __restrict__ oboxg, u64* __restrict__ kinitg){
#pragma clang fp contract(off)
  __shared__ u64 keys[CANDCAP];
  const int img = blockIdx.x;
  const int tid = threadIdx.x;
  const int M = min((int)cnt[img], CANDCAP);
  for (int i = tid; i < CANDCAP; i += 512)
    keys[i] = (i < M) ? cand[(long)img*CANDCAP + i] : 0ull;
  __syncthreads();
  for (int k = 2; k <= CANDCAP; k <<= 1){
    for (int j = k >> 1; j > 0; j >>= 1){
      int i = ((tid & ~(j-1)) << 1) | (tid & (j-1));
      int l = i | j;
      u64 a = keys[i], b = keys[l];
      bool desc = ((i & k) == 0);
      if (desc ? (a < b) : (a > b)){ keys[i] = b; keys[l] = a; }
      __syncthreads();
    }
  }
  // decode slots 0..511
  u64 key = keys[tid];
  bool pos = (key >> 32) != 0ull;
  float4 ob, cb;
  if (pos){
    u32 idxn = 0xFFFFFFFFu - (u32)(key & 0xFFFFFFFFull);
    const float* p = preds + ((long)img*NCAND + idxn)*PD;
    float cx = p[0], cy = p[1], w = p[2], h = p[3];
    float hw = w*0.5f, hh = h*0.5f;
    float X1 = cx-hw, Y1 = cy-hh, X2 = cx+hw, Y2 = cy+hh;
    float off = (float)clsArr[(long)img*NCAND + idxn] * 4096.0f;  // exact mul
    ob = make_float4(X1, Y1, X2, Y2);
    cb = make_float4(X1+off, Y1+off, X2+off, Y2+off);
  } else {
    ob = make_float4(0.f, 0.f, 0.f, 0.f);
    cb = make_float4(-4e8f, -4e8f, -4e8f, -4e8f);   // zero-area -> iou 0
  }
  oboxg[img*KC + tid] = ob;
  cboxg[img*KC + tid] = cb;
  u64 m = __ballot(pos);
  if ((tid & 63) == 0) kinitg[img*8 + (tid >> 6)] = m;
}

// ---------------- K4b: 512x512 suppression bit-matrix, parallel ----------------
// grid (8 row-groups, 8 img) x 256 thr. Boxes cached in 8KB LDS; each thread
// computes 2 u64 words (64 IOUs each). ~3us total vs ~40us inside old k_nms.
__global__ __launch_bounds__(256) void k_mat(const float4* __restrict__ cboxg,
    u64* __restrict__ rowsg){
#pragma clang fp contract(off)
  __shared__ float4 cb[KC];
  const int img = blockIdx.y;
  const int r0  = blockIdx.x*64;
  const int tid = threadIdx.x;
  for (int i = tid; i < KC; i += 256) cb[i] = cboxg[img*KC + i];
  __syncthreads();
  #pragma unroll
  for (int rep = 0; rep < 2; rep++){
    int t = tid + rep*256;
    int i = r0 + (t >> 3);
    int w = t & 7;
    float4 bi = cb[i];
    float areai = (bi.z - bi.x)*(bi.w - bi.y);
    u64 bits = 0ull;
    int jbase = w*64;
    for (int b = 0; b < 64; b++){
      int j = jbase + b;
      if (j > i){
        float4 bj = cb[j];
        float areaj = (bj.z - bj.x)*(bj.w - bj.y);
        float ltx = fmaxf(bi.x, bj.x), lty = fmaxf(bi.y, bj.y);
        float rbx = fminf(bi.z, bj.z), rby = fminf(bi.w, bj.w);
        float ww = fmaxf(rbx - ltx, 0.f);
        float hh = fmaxf(rby - lty, 0.f);
        float inter = ww*hh;
        float iou = inter / (areai + areaj - inter + 1e-7f);  // exact ref op order
        if (iou > 0.45f) bits |= (1ull << b);
      }
    }
    rowsg[((long)img*KC + i)*8 + w] = bits;
  }
}

// ---------------- K4c: serial greedy (prefetched) + stable compaction ----------------
__global__ __launch_bounds__(64) void k_greedy(const u64* __restrict__ rowsg,
    const u64* __restrict__ kinitg, const float4* __restrict__ oboxg,
    float* __restrict__ selbox, u32* __restrict__ selcnt){
  __shared__ u64 keeps[8];
  const int img  = blockIdx.x;
  const int lane = threadIdx.x;
  const u64* R = rowsg + (long)img*KC*8;
  u64 kw = (lane < 8) ? kinitg[img*8 + lane] : 0ull;
  u64 r  = (lane < 8) ? R[lane] : 0ull;
  for (int i = 0; i < KC; i++){
    u64 rn = (lane < 8 && i < KC-1) ? R[(i+1)*8 + lane] : 0ull;  // prefetch d=1
    u64 cw = shfl_u64(kw, i >> 6);
    if (((cw >> (i & 63)) & 1ull) && lane < 8) kw &= ~r;
    r = rn;
  }
  if (lane < 8) keeps[lane] = kw;
  __syncthreads();
  u64 kk[8];
  #pragma unroll
  for (int w = 0; w < 8; w++) kk[w] = keeps[w];
  int tot = 0;
  #pragma unroll
  for (int w = 0; w < 8; w++) tot += __popcll(kk[w]);
  for (int s = lane; s < KC; s += 64){
    int wi = s >> 6, bi = s & 63;
    bool kept = (kk[wi] >> bi) & 1ull;
    if (kept){
      int rank = 0;
      for (int w = 0; w < wi; w++) rank += __popcll(kk[w]);
      rank += __popcll(bi ? (kk[wi] & ((1ull << bi) - 1ull)) : 0ull);
      if (rank < MAXDET){
        float4 ob = oboxg[img*KC + s];
        float* sb = selbox + ((long)img*MAXDET + rank)*4;
        sb[0]=ob.x; sb[1]=ob.y; sb[2]=ob.z; sb[3]=ob.w;
      }
    }
  }
  if (lane == 0) selcnt[img] = (u32)min(tot, MAXDET);
}

// ---------------- K5a: level-1 projection, direct bf16 store ----------------
__global__ __launch_bounds__(256) void k_proj_b(const float* __restrict__ feat,
    const float* __restrict__ W1sub, __hip_bfloat16* __restrict__ G1,
    int C, int HW){
  const int img  = blockIdx.y;
  const int lane = threadIdx.x & 63;
  const int wave = threadIdx.x >> 6;
  const int p0   = blockIdx.x*64 + wave*16;
  if (p0 >= HW) return;
  const float* fimg = feat + (long)img*C*HW + p0;
  const float* Wp = W1sub + lane;
  float acc[16];
  #pragma unroll
  for (int k = 0; k < 16; k++) acc[k] = 0.f;
  #pragma unroll 2
  for (int c = 0; c < 128; c++){
    float w = Wp[(long)c*64];
    const float4* fp = (const float4*)(fimg + (long)c*HW);
    float4 a0 = fp[0], a1 = fp[1], a2 = fp[2], a3 = fp[3];
    acc[0]+=a0.x*w; acc[1]+=a0.y*w; acc[2]+=a0.z*w; acc[3]+=a0.w*w;
    acc[4]+=a1.x*w; acc[5]+=a1.y*w; acc[6]+=a1.z*w; acc[7]+=a1.w*w;
    acc[8]+=a2.x*w; acc[9]+=a2.y*w; acc[10]+=a2.z*w; acc[11]+=a2.w*w;
    acc[12]+=a3.x*w; acc[13]+=a3.y*w; acc[14]+=a3.z*w; acc[15]+=a3.w*w;
  }
  __hip_bfloat16* g = G1 + ((long)img*PX1 + p0)*64 + lane;
  #pragma unroll
  for (int k = 0; k < 16; k++) g[(long)k*64] = __float2bfloat16(acc[k]);
}

// ---------------- K5b: levels 2-4 projection, K-split, f32 atomic acc ----------------
__global__ __launch_bounds__(256) void k_proj_a(const float* __restrict__ feat,
    const float* __restrict__ W1sub, float* __restrict__ Gacc,
    int C, int HW, int accoff){
  const int img  = blockIdx.z;
  const int c0   = blockIdx.y * 128;
  const int lane = threadIdx.x & 63;
  const int wave = threadIdx.x >> 6;
  const int p0   = blockIdx.x*64 + wave*16;
  if (p0 >= HW) return;
  const float* fimg = feat + ((long)img*C + c0)*HW + p0;
  const float* Wp = W1sub + (long)c0*64 + lane;
  float acc[16];
  #pragma unroll
  for (int k = 0; k < 16; k++) acc[k] = 0.f;
  #pragma unroll 2
  for (int c = 0; c < 128; c++){
    float w = Wp[(long)c*64];
    const float4* fp = (const float4*)(fimg + (long)c*HW);
    float4 a0 = fp[0], a1 = fp[1], a2 = fp[2], a3 = fp[3];
    acc[0]+=a0.x*w; acc[1]+=a0.y*w; acc[2]+=a0.z*w; acc[3]+=a0.w*w;
    acc[4]+=a1.x*w; acc[5]+=a1.y*w; acc[6]+=a1.z*w; acc[7]+=a1.w*w;
    acc[8]+=a2.x*w; acc[9]+=a2.y*w; acc[10]+=a2.z*w; acc[11]+=a2.w*w;
    acc[12]+=a3.x*w; acc[13]+=a3.y*w; acc[14]+=a3.z*w; acc[15]+=a3.w*w;
  }
  float* g = Gacc + ((long)img*PXA + accoff + p0)*64 + lane;
  #pragma unroll
  for (int k = 0; k < 16; k++) atomicAdd(g + (long)k*64, acc[k]);
}

// ---------------- K6: fused ROI-gather + bias + leaky + layer2 + assembly ----------------
template <typename T>
__device__ __forceinline__ float gread(const T* g, long off, int lane);
template <> __device__ __forceinline__ float gread<__hip_bfloat16>(
    const __hip_bfloat16* g, long off, int lane){ return __bfloat162float(g[off*64+lane]); }
template <> __device__ __forceinline__ float gread<float>(
    const float* g, long off, int lane){ return g[off*64+lane]; }

template <typename T>
__device__ __forceinline__ void roi_level(const T* __restrict__ g,
    int Hl, int Wl, float scale, float x1, float y1, float x2, float y2,
    int lane, float& h){
  float bx1=x1*scale, by1=y1*scale, bx2=x2*scale, by2=y2*scale;
  float rw=fmaxf(bx2-bx1,1.f), rh=fmaxf(by2-by1,1.f);
  float ys[2]={by1+rh*0.25f, by1+rh*0.75f};
  float xs[2]={bx1+rw*0.25f, bx1+rw*0.75f};
  #pragma unroll
  for (int pt = 0; pt < 4; pt++){
    float y=ys[pt>>1], x=xs[pt&1];
    if ((y>-1.f)&&(y<(float)Hl)&&(x>-1.f)&&(x<(float)Wl)){   // wave-uniform branch
      float yc=fmaxf(y,0.f), xc=fmaxf(x,0.f);
      int y0=(int)fminf(floorf(yc),(float)(Hl-1));
      int x0=(int)fminf(floorf(xc),(float)(Wl-1));
      int y1i=min(y0+1,Hl-1), x1i=min(x0+1,Wl-1);
      float ly=yc-(float)y0, lx=xc-(float)x0;
      float hy=1.f-ly, hx=1.f-lx;
      h += (hy*hx*0.25f)*gread(g,(long)(y0*Wl+x0),lane);
      h += (hy*lx*0.25f)*gread(g,(long)(y0*Wl+x1i),lane);
      h += (ly*hx*0.25f)*gread(g,(long)(y1i*Wl+x0),lane);
      h += (ly*lx*0.25f)*gread(g,(long)(y1i*Wl+x1i),lane);
    }
  }
}

__global__ __launch_bounds__(256) void k_roi_mlp(const __hip_bfloat16* __restrict__ G1,
    const float* __restrict__ Gacc,
    const float* __restrict__ selbox, const u32* __restrict__ selcnt,
    const float* __restrict__ b1, const float* __restrict__ W2,
    const float* __restrict__ b2, float* __restrict__ out){
  const int img  = blockIdx.y;
  const int wave = threadIdx.x >> 6;
  const int lane = threadIdx.x & 63;
  const int slot = blockIdx.x*4 + wave;
  if (slot >= MAXDET) return;
  float* o = out + ((long)img*MAXDET + slot)*68;
  if (slot >= (int)selcnt[img]){
    o[4+lane] = 0.f;
    if (lane < 4) o[lane] = 0.f;
    return;
  }
  const float* sb = selbox + ((long)img*MAXDET + slot)*4;
  float x1 = sb[0], y1 = sb[1], x2 = sb[2], y2 = sb[3];
  const __hip_bfloat16* G1i = G1 + (long)img*PX1*64;
  const float* Gai = Gacc + (long)img*PXA*64;
  float h = 0.f;
  roi_level(G1i,            96, 96, 0.125f,    x1,y1,x2,y2, lane, h);
  roi_level(Gai,            48, 48, 0.0625f,   x1,y1,x2,y2, lane, h);
  roi_level(Gai + 2304*64,  24, 24, 0.03125f,  x1,y1,x2,y2, lane, h);
  roi_level(Gai + 2880*64,  12, 12, 0.015625f, x1,y1,x2,y2, lane, h);
  float h1 = leaky(h + b1[lane]);
  float c = 0.f;
  #pragma unroll 8
  for (int k = 0; k < 64; k++){
    float hk = __shfl(h1, k, 64);
    c += hk * W2[k*64 + lane];
  }
  o[4+lane] = leaky(c + b2[lane]);
  if (lane < 4) o[lane] = sb[lane] / 768.0f;
}

// ---------------- workspace layout (bytes) ----------------
// 0         hist    u32[8][2048]       65536
// 65536     cnt     u32[8]             256 (padded)
// 65792     thr     u32[8]             256
// 66048     selbox  f32[8][300][4]     38400
// 104448    selcnt  u32[8]             256
// 104704    sbits   u32[8][36720]      1175040
// 1279744   cls     i32[8][36720]      1175040
// 2454784   cand    u64[8][1024]       65536
// 2520320   cbox    float4[8][512]     65536
// 2585856   obox    float4[8][512]     65536
// 2651392   kinit   u64[8][8]          512
// 2651904   rowsg   u64[8][512][8]     262144
// 2914048   G1      bf16[8][9216][64]  9437184
// 12351232  Gacc    f32[8][3024][64]   6193152   -> total 18.5 MB

extern "C" void kernel_launch(void* const* d_in, const int* in_sizes, int n_in,
                              void* d_out, int out_size, void* d_ws, size_t ws_size,
                              hipStream_t stream){
  const float* preds = (const float*)d_in[0];
  const float* f1 = (const float*)d_in[1];
  const float* f2 = (const float*)d_in[2];
  const float* f3 = (const float*)d_in[3];
  const float* f4 = (const float*)d_in[4];
  const float* W1 = (const float*)d_in[5];
  const float* b1 = (const float*)d_in[6];
  const float* W2 = (const float*)d_in[7];
  const float* b2 = (const float*)d_in[8];
  float* out = (float*)d_out;
  char* ws = (char*)d_ws;
  u32* hist   = (u32*)(ws + 0);
  u32* cnt    = (u32*)(ws + 65536);
  u32* thr    = (u32*)(ws + 65792);
  float* selb = (float*)(ws + 66048);
  u32* selc   = (u32*)(ws + 104448);
  u32* sbits  = (u32*)(ws + 104704);
  int* clsA   = (int*)(ws + 1279744);
  u64* cand   = (u64*)(ws + 2454784);
  float4* cbox= (float4*)(ws + 2520320);
  float4* obox= (float4*)(ws + 2585856);
  u64* kinit  = (u64*)(ws + 2651392);
  u64* rowsg  = (u64*)(ws + 2651904);
  __hip_bfloat16* G1 = (__hip_bfloat16*)(ws + 2914048);
  float* Gacc = (float*)(ws + 12351232);

  hipMemsetAsync(ws, 0, 65792, stream);                       // hist + cnt
  hipMemsetAsync(Gacc, 0, (size_t)B_IMG*PXA*64*4, stream);    // K-split accumulator

  dim3 gs((NCAND*4 + 255)/256, B_IMG);
  k_score<<<gs, 256, 0, stream>>>(preds, sbits, clsA, hist);
  k_thresh<<<B_IMG, 64, 0, stream>>>(hist, thr);
  dim3 g3((NCAND+255)/256, B_IMG);
  k_gather<<<g3, 256, 0, stream>>>(sbits, thr, cnt, cand);
  k_sort<<<B_IMG, 512, 0, stream>>>(preds, clsA, cand, cnt, cbox, obox, kinit);
  k_mat<<<dim3(8, B_IMG), 256, 0, stream>>>(cbox, rowsg);
  k_greedy<<<B_IMG, 64, 0, stream>>>(rowsg, kinit, obox, selb, selc);
  // projection (independent of NMS result)
  k_proj_b<<<dim3(144, B_IMG),    256, 0, stream>>>(f1, W1,          G1, 128, 96*96);
  k_proj_a<<<dim3(36, 2, B_IMG),  256, 0, stream>>>(f2, W1 + 128*64, Gacc, 256, 48*48, 0);
  k_proj_a<<<dim3(9,  4, B_IMG),  256, 0, stream>>>(f3, W1 + 384*64, Gacc, 512, 24*24, 2304);
  k_proj_a<<<dim3(3,  8, B_IMG),  256, 0, stream>>>(f4, W1 + 896*64, Gacc, 1024, 12*12, 2880);
  k_roi_mlp<<<dim3((MAXDET+3)/4, B_IMG), 256, 0, stream>>>(G1, Gacc, selb, selc, b1, W2, b2, out);
}

// Round 6
// 534.461 us; speedup vs baseline: 1.1757x; 1.1757x over previous
//
#include <hip/hip_runtime.h>
#include <hip/hip_bf16.h>
#include <cstdint>

#define B_IMG   8
#define NCAND   36720
#define PD      85
#define NCLS    80
#define KC      512
#define MAXDET  300
#define NBUCK   2048
#define CANDCAP 1024      // gathered count is ~512 + one-bucket (<~40): 1024 is safe
#define PX1     9216      // 96*96 pixels, level 1 (bf16 G1)
#define PXA     3024      // 48*48 + 24*24 + 12*12, levels 2-4 (f32 Gacc)

typedef unsigned int u32;
typedef unsigned long long u64;

__device__ __forceinline__ float leaky(float x){ return x >= 0.f ? x : 0.01f*x; }

__device__ __forceinline__ u64 shfl_u64(u64 v, int lane){
  int lo = __shfl((int)(u32)(v & 0xFFFFFFFFull), lane, 64);
  int hi = __shfl((int)(u32)(v >> 32), lane, 64);
  return ((u64)(u32)hi << 32) | (u64)(u32)lo;
}
__device__ __forceinline__ u64 shfl_xor_u64(u64 v, int mask){
  int lo = __shfl_xor((int)(u32)(v & 0xFFFFFFFFull), mask, 64);
  int hi = __shfl_xor((int)(u32)(v >> 32), mask, 64);
  return ((u64)(u32)hi << 32) | (u64)(u32)lo;
}

// ---------------- K1: score + argmax-cls, 4 lanes/candidate, no LDS ----------------
__global__ __launch_bounds__(256) void k_score(const float* __restrict__ preds,
    u32* __restrict__ sbits, int* __restrict__ clsArr, u32* __restrict__ hist){
  const int img = blockIdx.y;
  const int tid = threadIdx.x;
  const int q   = tid & 3;
  const int ci  = blockIdx.x*64 + (tid >> 2);
  if (ci >= NCAND) return;
  const float* p = preds + ((long)img*NCAND + ci)*PD;
  float obj = p[4];
  const float* pc = p + 5 + q;
  u64 best = 0ull;
  #pragma unroll
  for (int k = 0; k < 20; k++){
    float v = pc[4*k] * obj;
    u32 cls = (u32)(q + 4*k);
    u64 key = ((u64)__float_as_uint(v) << 32) | (u64)(~cls);
    if (key > best) best = key;     // strict >: first max wins within lane
  }
  #pragma unroll
  for (int off = 1; off <= 2; off <<= 1){
    u64 o = shfl_xor_u64(best, off);
    if (o > best) best = o;         // tie: larger ~cls = smaller cls wins
  }
  if (q == 0){
    u32 bits = (u32)(best >> 32);
    bool valid = (obj > 0.596f) && (__uint_as_float(bits) > 0.596f);
    u32 sb = valid ? bits : 0u;     // valid scores in (0.596,1)
    int cls = (int)(~(u32)(best & 0xFFFFFFFFull));
    long gi = (long)img*NCAND + ci;
    sbits[gi]  = sb;
    clsArr[gi] = cls;
    if (sb) atomicAdd(&hist[img*NBUCK + ((sb - 0x3F000000u) >> 12)], 1u);
  }
}

// ---------------- K2: per-image bit-threshold covering top-512 ----------------
__global__ __launch_bounds__(64) void k_thresh(const u32* __restrict__ hist,
                                               u32* __restrict__ thr){
  const int img = blockIdx.x;
  const int lane = threadIdx.x;
  const u32* h = hist + img*NBUCK;
  u32 acc = 0; u32 result = 0x3F000000u; bool found = false;
  for (int g = NBUCK/64 - 1; g >= 0 && !found; g--){
    u32 v = h[g*64 + lane];
    u32 s = v;
    #pragma unroll
    for (int off = 1; off < 64; off <<= 1){
      u32 t = __shfl_down(s, off, 64);
      s += (lane + off < 64) ? t : 0u;
    }
    u64 mask = __ballot(acc + s >= KC);
    if (mask){
      int hl = 63 - __clzll(mask);
      result = 0x3F000000u + ((u32)(g*64 + hl) << 12);
      found = true;
    }
    acc += __shfl(s, 0, 64);
  }
  if (lane == 0) thr[img] = result;
}

// ---------------- K3: gather candidates >= threshold as sortable keys ----------------
__global__ __launch_bounds__(256) void k_gather(const u32* __restrict__ sbits,
    const u32* __restrict__ thr, u32* __restrict__ cnt, u64* __restrict__ cand){
  int img = blockIdx.y;
  int n = blockIdx.x*256 + threadIdx.x;
  if (n >= NCAND) return;
  u32 bits = sbits[(long)img*NCAND + n];
  if (bits && bits >= thr[img]){
    u32 pos = atomicAdd(&cnt[img], 1u);
    if (pos < CANDCAP)
      cand[(long)img*CANDCAP + pos] = ((u64)bits << 32) | (u64)(0xFFFFFFFFu - (u32)n);
  }
}

// ---------------- K4: fused NMS: rank -> decode -> IOU matrix -> greedy -> compact ----
// One 512-thread block per image; ALL state in LDS (~58 KB). Rank-by-count
// replaces the 55-barrier bitonic (keys are distinct: idx embedded). Greedy
// uses a lane-local blocked update: per 64-bit word-block, broadcast the keep
// word once; each lane then updates both the decision word and its owned word
// from LDS rows -- per-iteration chain is ~14 VALU cycles, no shfl, no global
// (round-5's k_greedy burned ~570 cyc/iter on serialized cross-XCD loads).
__global__ __launch_bounds__(512) void k_nms(const float* __restrict__ preds,
    const int* __restrict__ clsArr, const u64* __restrict__ cand,
    const u32* __restrict__ cnt, float* __restrict__ selbox, u32* __restrict__ selcnt){
#pragma clang fp contract(off)
  __shared__ __align__(16) u64 keys[CANDCAP];      // 8 KB
  __shared__ float4 cbs[KC];                       // 8 KB  class-offset boxes
  __shared__ float4 obs[KC];                       // 8 KB  original boxes
  __shared__ u64 lrows[KC*8];                      // 32 KB suppression matrix
  __shared__ u64 kmask[8];
  __shared__ u64 keepw[8];
  const int img = blockIdx.x;
  const int tid = threadIdx.x;
  const int M = min((int)cnt[img], CANDCAP);
  keys[tid]       = (tid < M)       ? cand[(long)img*CANDCAP + tid]       : 0ull;
  keys[tid + 512] = (tid + 512 < M) ? cand[(long)img*CANDCAP + tid + 512] : 0ull;
  cbs[tid] = make_float4(-4e8f, -4e8f, -4e8f, -4e8f);   // zero-area -> iou 0
  obs[tid] = make_float4(0.f, 0.f, 0.f, 0.f);
  if (tid < 8) kmask[tid] = 0ull;
  __syncthreads();
  // ---- rank by count (desc): rank = #{keys strictly greater} ----
  u64 k0 = keys[tid], k1 = keys[tid + 512];
  int r0 = 0, r1 = 0;
  const ulonglong2* kv = (const ulonglong2*)keys;
  for (int j = 0; j < CANDCAP/2; j++){              // wave-uniform b128 broadcast
    ulonglong2 kk = kv[j];
    r0 += (kk.x > k0) + (kk.y > k0);
    r1 += (kk.x > k1) + (kk.y > k1);
  }
  // ---- decode my keys into ranked slots ----
  #pragma unroll
  for (int t = 0; t < 2; t++){
    u64 key = t ? k1 : k0;
    int rank = t ? r1 : r0;
    if ((key >> 32) != 0ull && rank < KC){
      u32 idxn = 0xFFFFFFFFu - (u32)(key & 0xFFFFFFFFull);
      const float* p = preds + ((long)img*NCAND + idxn)*PD;
      float cx = p[0], cy = p[1], w = p[2], h = p[3];
      float hw = w*0.5f, hh = h*0.5f;               // exact
      float X1 = cx-hw, Y1 = cy-hh, X2 = cx+hw, Y2 = cy+hh;
      float off = (float)clsArr[(long)img*NCAND + idxn] * 4096.0f;  // exact
      obs[rank] = make_float4(X1, Y1, X2, Y2);
      cbs[rank] = make_float4(X1+off, Y1+off, X2+off, Y2+off);
      atomicOr(&kmask[rank >> 6], 1ull << (rank & 63));
    }
  }
  __syncthreads();
  // ---- suppression matrix: thread = row i; j-loop is wave-uniform (LDS bcast) ----
  {
    const int i = tid;
    float4 bi = cbs[i];
    float areai = (bi.z - bi.x)*(bi.w - bi.y);
    for (int w = 0; w < 8; w++){
      u64 bits = 0ull;
      int jbase = w*64;
      for (int b = 0; b < 64; b++){
        int j = jbase + b;
        if (j > i){
          float4 bj = cbs[j];
          float areaj = (bj.z - bj.x)*(bj.w - bj.y);
          float ltx = fmaxf(bi.x, bj.x), lty = fmaxf(bi.y, bj.y);
          float rbx = fminf(bi.z, bj.z), rby = fminf(bi.w, bj.w);
          float ww = fmaxf(rbx - ltx, 0.f);
          float hh = fmaxf(rby - lty, 0.f);
          float inter = ww*hh;
          float iou = inter / (areai + areaj - inter + 1e-7f);  // exact ref op order
          if (iou > 0.45f) bits |= (1ull << b);
        }
      }
      lrows[i*8 + w] = bits;
    }
  }
  __syncthreads();
  // ---- greedy: wave 0, lane-local blocked update ----
  if (tid < 64){
    const int lane = tid;
    const int w = lane & 7;                 // word this lane owns (lanes 8-63 duplicate)
    u64 kw_own = kmask[w];
    for (int b = 0; b < 8; b++){
      u64 kwb = shfl_u64(kw_own, b);        // lane b owns word b (fresh)
      for (int g = 0; g < 8; g++){
        u64 rdec[8], rown[8];
        #pragma unroll
        for (int k = 0; k < 8; k++){
          int i = b*64 + g*8 + k;
          rdec[k] = lrows[i*8 + b];         // decision word (LDS broadcast)
          rown[k] = lrows[i*8 + w];         // owned word
        }
        #pragma unroll
        for (int k = 0; k < 8; k++){
          int il = g*8 + k;
          if ((kwb >> il) & 1ull){
            kwb    &= ~rdec[k];             // critical chain: local regs only
            kw_own &= ~rown[k];             // off-chain until block boundary
          }
        }
      }
    }
    if (lane < 8) keepw[lane] = kw_own;
  }
  __syncthreads();
  // ---- stable compaction (scores already desc => top_k(sc2,300)) ----
  {
    u64 kk[8];
    #pragma unroll
    for (int w = 0; w < 8; w++) kk[w] = keepw[w];
    const int s = tid;
    const int wi = s >> 6, bi = s & 63;
    bool kept = (kk[wi] >> bi) & 1ull;
    if (kept){
      int rank = 0;
      for (int w = 0; w < wi; w++) rank += __popcll(kk[w]);
      rank += __popcll(bi ? (kk[wi] & ((1ull << bi) - 1ull)) : 0ull);
      if (rank < MAXDET){
        float4 ob = obs[s];
        float* sb = selbox + ((long)img*MAXDET + rank)*4;
        sb[0]=ob.x; sb[1]=ob.y; sb[2]=ob.z; sb[3]=ob.w;
      }
    }
    if (tid == 0){
      int tot = 0;
      #pragma unroll
      for (int w = 0; w < 8; w++) tot += __popcll(kk[w]);
      selcnt[img] = (u32)min(tot, MAXDET);
    }
  }
}

// ---------------- K5: unified projection, all 4 levels in one launch ----------------
// blockIdx.x = flat segment: L1 144 px-tiles (C=128, direct bf16 store);
// L2 36x4, L3 9x8, L4 3x16 (64-ch K-chunks, f32 atomic accumulate).
// 408 segments x 8 img = 3264 blocks in ONE dispatch: one ramp, levels overlap.
__global__ __launch_bounds__(256) void k_proj(const float* __restrict__ f1,
    const float* __restrict__ f2, const float* __restrict__ f3,
    const float* __restrict__ f4, const float* __restrict__ W1,
    __hip_bfloat16* __restrict__ G1, float* __restrict__ Gacc){
  const int img = blockIdx.y;
  const int seg = blockIdx.x;
  const float* feat; int C, HW, px, chunk, Woff, accoff, iters; bool lvl1;
  if (seg < 144){      feat=f1; C=128;  HW=9216; px=seg;        chunk=0;      Woff=0;   accoff=0;    iters=128; lvl1=true; }
  else if (seg < 288){ int s=seg-144; feat=f2; C=256;  HW=2304; px=s>>2; chunk=s&3;  Woff=128; accoff=0;    iters=64; lvl1=false; }
  else if (seg < 360){ int s=seg-288; feat=f3; C=512;  HW=576;  px=s>>3; chunk=s&7;  Woff=384; accoff=2304; iters=64; lvl1=false; }
  else {               int s=seg-360; feat=f4; C=1024; HW=144;  px=s>>4; chunk=s&15; Woff=896; accoff=2880; iters=64; lvl1=false; }
  const int lane = threadIdx.x & 63;
  const int wave = threadIdx.x >> 6;
  const int p0 = px*64 + wave*16;
  if (p0 >= HW) return;
  const float* fimg = feat + ((long)img*C + chunk*64)*HW + p0;
  const float* Wp = W1 + (long)(Woff + chunk*64)*64 + lane;
  float acc[16];
  #pragma unroll
  for (int k = 0; k < 16; k++) acc[k] = 0.f;
  #pragma unroll 2
  for (int c = 0; c < iters; c++){
    float w = Wp[(long)c*64];
    const float4* fp = (const float4*)(fimg + (long)c*HW);
    float4 a0 = fp[0], a1 = fp[1], a2 = fp[2], a3 = fp[3];
    acc[0]+=a0.x*w; acc[1]+=a0.y*w; acc[2]+=a0.z*w; acc[3]+=a0.w*w;
    acc[4]+=a1.x*w; acc[5]+=a1.y*w; acc[6]+=a1.z*w; acc[7]+=a1.w*w;
    acc[8]+=a2.x*w; acc[9]+=a2.y*w; acc[10]+=a2.z*w; acc[11]+=a2.w*w;
    acc[12]+=a3.x*w; acc[13]+=a3.y*w; acc[14]+=a3.z*w; acc[15]+=a3.w*w;
  }
  if (lvl1){
    __hip_bfloat16* g = G1 + ((long)img*PX1 + p0)*64 + lane;
    #pragma unroll
    for (int k = 0; k < 16; k++) g[(long)k*64] = __float2bfloat16(acc[k]);
  } else {
    float* g = Gacc + ((long)img*PXA + accoff + p0)*64 + lane;
    #pragma unroll
    for (int k = 0; k < 16; k++) atomicAdd(g + (long)k*64, acc[k]);
  }
}

// ---------------- K6: fused ROI-gather + bias + leaky + layer2 + assembly ----------------
template <typename T>
__device__ __forceinline__ float gread(const T* g, long off, int lane);
template <> __device__ __forceinline__ float gread<__hip_bfloat16>(
    const __hip_bfloat16* g, long off, int lane){ return __bfloat162float(g[off*64+lane]); }
template <> __device__ __forceinline__ float gread<float>(
    const float* g, long off, int lane){ return g[off*64+lane]; }

template <typename T>
__device__ __forceinline__ void roi_level(const T* __restrict__ g,
    int Hl, int Wl, float scale, float x1, float y1, float x2, float y2,
    int lane, float& h){
  float bx1=x1*scale, by1=y1*scale, bx2=x2*scale, by2=y2*scale;
  float rw=fmaxf(bx2-bx1,1.f), rh=fmaxf(by2-by1,1.f);
  float ys[2]={by1+rh*0.25f, by1+rh*0.75f};
  float xs[2]={bx1+rw*0.25f, bx1+rw*0.75f};
  #pragma unroll
  for (int pt = 0; pt < 4; pt++){
    float y=ys[pt>>1], x=xs[pt&1];
    if ((y>-1.f)&&(y<(float)Hl)&&(x>-1.f)&&(x<(float)Wl)){   // wave-uniform branch
      float yc=fmaxf(y,0.f), xc=fmaxf(x,0.f);
      int y0=(int)fminf(floorf(yc),(float)(Hl-1));
      int x0=(int)fminf(floorf(xc),(float)(Wl-1));
      int y1i=min(y0+1,Hl-1), x1i=min(x0+1,Wl-1);
      float ly=yc-(float)y0, lx=xc-(float)x0;
      float hy=1.f-ly, hx=1.f-lx;
      h += (hy*hx*0.25f)*gread(g,(long)(y0*Wl+x0),lane);
      h += (hy*lx*0.25f)*gread(g,(long)(y0*Wl+x1i),lane);
      h += (ly*hx*0.25f)*gread(g,(long)(y1i*Wl+x0),lane);
      h += (ly*lx*0.25f)*gread(g,(long)(y1i*Wl+x1i),lane);
    }
  }
}

__global__ __launch_bounds__(256) void k_roi_mlp(const __hip_bfloat16* __restrict__ G1,
    const float* __restrict__ Gacc,
    const float* __restrict__ selbox, const u32* __restrict__ selcnt,
    const float* __restrict__ b1, const float* __restrict__ W2,
    const float* __restrict__ b2, float* __restrict__ out){
  const int img  = blockIdx.y;
  const int wave = threadIdx.x >> 6;
  const int lane = threadIdx.x & 63;
  const int slot = blockIdx.x*4 + wave;
  if (slot >= MAXDET) return;
  float* o = out + ((long)img*MAXDET + slot)*68;
  if (slot >= (int)selcnt[img]){
    o[4+lane] = 0.f;
    if (lane < 4) o[lane] = 0.f;
    return;
  }
  const float* sb = selbox + ((long)img*MAXDET + slot)*4;
  float x1 = sb[0], y1 = sb[1], x2 = sb[2], y2 = sb[3];
  const __hip_bfloat16* G1i = G1 + (long)img*PX1*64;
  const float* Gai = Gacc + (long)img*PXA*64;
  float h = 0.f;
  roi_level(G1i,            96, 96, 0.125f,    x1,y1,x2,y2, lane, h);
  roi_level(Gai,            48, 48, 0.0625f,   x1,y1,x2,y2, lane, h);
  roi_level(Gai + 2304*64,  24, 24, 0.03125f,  x1,y1,x2,y2, lane, h);
  roi_level(Gai + 2880*64,  12, 12, 0.015625f, x1,y1,x2,y2, lane, h);
  float h1 = leaky(h + b1[lane]);
  float c = 0.f;
  #pragma unroll 8
  for (int k = 0; k < 64; k++){
    float hk = __shfl(h1, k, 64);
    c += hk * W2[k*64 + lane];
  }
  o[4+lane] = leaky(c + b2[lane]);
  if (lane < 4) o[lane] = sb[lane] / 768.0f;
}

// ---------------- workspace layout (bytes) ----------------
// 0         hist    u32[8][2048]       65536
// 65536     cnt     u32[8]             256 (padded)
// 65792     thr     u32[8]             256
// 66048     selbox  f32[8][300][4]     38400
// 104448    selcnt  u32[8]             256
// 104704    sbits   u32[8][36720]      1175040
// 1279744   cls     i32[8][36720]      1175040
// 2454784   cand    u64[8][1024]       65536
// 2520320   G1      bf16[8][9216][64]  9437184
// 11957504  Gacc    f32[8][3024][64]   6193152   -> total ~18.2 MB

extern "C" void kernel_launch(void* const* d_in, const int* in_sizes, int n_in,
                              void* d_out, int out_size, void* d_ws, size_t ws_size,
                              hipStream_t stream){
  const float* preds = (const float*)d_in[0];
  const float* f1 = (const float*)d_in[1];
  const float* f2 = (const float*)d_in[2];
  const float* f3 = (const float*)d_in[3];
  const float* f4 = (const float*)d_in[4];
  const float* W1 = (const float*)d_in[5];
  const float* b1 = (const float*)d_in[6];
  const float* W2 = (const float*)d_in[7];
  const float* b2 = (const float*)d_in[8];
  float* out = (float*)d_out;
  char* ws = (char*)d_ws;
  u32* hist   = (u32*)(ws + 0);
  u32* cnt    = (u32*)(ws + 65536);
  u32* thr    = (u32*)(ws + 65792);
  float* selb = (float*)(ws + 66048);
  u32* selc   = (u32*)(ws + 104448);
  u32* sbits  = (u32*)(ws + 104704);
  int* clsA   = (int*)(ws + 1279744);
  u64* cand   = (u64*)(ws + 2454784);
  __hip_bfloat16* G1 = (__hip_bfloat16*)(ws + 2520320);
  float* Gacc = (float*)(ws + 11957504);

  hipMemsetAsync(ws, 0, 65792, stream);                       // hist + cnt
  hipMemsetAsync(Gacc, 0, (size_t)B_IMG*PXA*64*4, stream);    // K-split accumulator

  dim3 gs((NCAND*4 + 255)/256, B_IMG);
  k_score<<<gs, 256, 0, stream>>>(preds, sbits, clsA, hist);
  k_thresh<<<B_IMG, 64, 0, stream>>>(hist, thr);
  dim3 g3((NCAND+255)/256, B_IMG);
  k_gather<<<g3, 256, 0, stream>>>(sbits, thr, cnt, cand);
  k_nms<<<B_IMG, 512, 0, stream>>>(preds, clsA, cand, cnt, selb, selc);
  k_proj<<<dim3(408, B_IMG), 256, 0, stream>>>(f1, f2, f3, f4, W1, G1, Gacc);
  k_roi_mlp<<<dim3((MAXDET+3)/4, B_IMG), 256, 0, stream>>>(G1, Gacc, selb, selc, b1, W2, b2, out);
}